// Round 15
// baseline (137.242 us; speedup 1.0000x reference)
//
#include <hip/hip_runtime.h>
#include <math.h>

#define CIN   16
#define COUT  64
#define H     256
#define W     256
#define OH    254
#define OW    254
#define NTAP  9
#define HWSZ  (H * W)
#define RING  10
#define SROW  136       // f16x8 slots per ring row: 2 g * 68

typedef _Float16 f16x8  __attribute__((ext_vector_type(8)));
typedef float    f32x16 __attribute__((ext_vector_type(16)));

// weight pack: [tap 9][msub 2][lane 64][e 8] fp16; co=(l&31)+32m, cin=8*(l>>5)+e
__global__ void wpack_kernel(const float* __restrict__ w, _Float16* __restrict__ wpk) {
    int idx = blockIdx.x * 256 + threadIdx.x;   // 0..9215
    if (idx >= NTAP * 2 * 64 * 8) return;
    int e = idx & 7, l = (idx >> 3) & 63, m = (idx >> 9) & 1, t = idx >> 10;
    int co  = (l & 31) + 32 * m;
    int cin = 8 * (l >> 5) + e;
    wpk[idx] = (_Float16)w[((co * CIN + cin) * 3 + t / 3) * 3 + (t % 3)];
}

__device__ __forceinline__ float tanh_fast(float v) {
    float e = __expf(2.0f * v);
    return 1.0f - 2.0f * __builtin_amdgcn_rcpf(e + 1.0f);
}
__device__ __forceinline__ float min3f(float a, float b, float c) {
    return fminf(fminf(a, b), c);   // clang fuses to v_min3_f32
}

// 256 thr = 4 waves = 2 m-halves x 2 px-slices. Block = 64-px column x ~85-row
// strip; 4 output rows per wave-iter (acc[4], ro-interleaved MFMA chains).
// 3 blocks/CU; one barrier per 4 rows; ring=10 input rows in LDS.
__global__ __launch_bounds__(256, 3) void conv_mfma_kernel(
        const float* __restrict__ x, const f16x8* __restrict__ wpk,
        const float* __restrict__ bias, float* __restrict__ out) {
    __shared__ f16x8 ring[RING * SROW];        // 21,760 B
    __shared__ float xmin[2][2][2][4][32];     // 4,096 B [par][m][slice][ro][px]

    const int tid  = threadIdx.x;
    const int lane = tid & 63;

    int bid = blockIdx.x;
    int nb  = (bid & 7) * 96 + (bid >> 3);     // 768 = 8*96 bijective XCD swizzle
    const int img   = nb / 12;
    const int rem   = nb - 12 * img;
    const int c     = rem & 3;                 // 64-px column
    const int strip = rem >> 2;                // row strip (85/85/84 rows)
    const int r0    = strip * 85;
    const int nit   = (strip == 2) ? 21 : 22;  // 4-row iterations
    const int base  = 64 * c;

    const float* xb = x + (size_t)img * CIN * HWSZ;

    const int wv    = tid >> 6;
    const int m     = wv & 1;                  // cout half
    const int slice = wv >> 1;                 // 32-px slice
    const int l31   = lane & 31;
    const int g2    = lane >> 5;

    // ---- weights: this wave's m-half -> 36 VGPRs ----
    f16x8 wreg[NTAP];
#pragma unroll
    for (int t = 0; t < NTAP; ++t)
        wreg[t] = wpk[(t * 2 + m) * 64 + lane];

    // bias C-fragment: col=l31(px), row=(q&3)+8*(q>>2)+4*g2+32m (co)
    f32x16 cbias;
#pragma unroll
    for (int q = 0; q < 16; ++q)
        cbias[q] = bias[(q & 3) + 8 * (q >> 2) + 4 * g2 + 32 * m];

    // ---- staging decode: main = (srow, sg, px-pair), halo = (hrow, hcin, hp) ----
    const int srow = tid >> 6;                 // row in 4-row group
    const int sg   = (tid >> 5) & 1;           // cin half
    const int sp   = tid & 31;                 // px pair
    const int spx  = base + 2 * sp;            // <= 254, always in-bounds
    const bool hact = tid < 128;
    const int hrow = (tid >> 5) & 3;
    const int hcin = tid & 15;
    const int hp   = (tid >> 4) & 1;
    int hpx = base + 64 + hp; if (hpx > 255) hpx = 255;   // c=3 halo clamp
    const int hslot = (hcin >> 3) * 68 + 64 + hp;
    const int hsub  = hcin & 7;

    float2 vm[8];
    float  hv;

#define SLOADM(rowAbs) { \
    int r_ = (rowAbs); if (r_ > 255) r_ = 255; \
    const float* p_ = xb + (size_t)r_ * W + spx; \
    _Pragma("unroll") \
    for (int ci = 0; ci < 8; ++ci) vm[ci] = *(const float2*)(p_ + (size_t)(8 * sg + ci) * HWSZ); }

#define SLOADH(rowAbs) { \
    int r_ = (rowAbs); if (r_ > 255) r_ = 255; \
    hv = xb[(size_t)hcin * HWSZ + (size_t)r_ * W + hpx]; }

#define SWRITEM(slot) { \
    f16x8 q0, q1; \
    _Pragma("unroll") \
    for (int ci = 0; ci < 8; ++ci) { q0[ci] = (_Float16)vm[ci].x; q1[ci] = (_Float16)vm[ci].y; } \
    int b_ = (slot) * SROW + sg * 68 + 2 * sp; \
    ring[b_] = q0; ring[b_ + 1] = q1; }

#define SWRITEH(slot) \
    ((_Float16*)ring)[((slot) * SROW + hslot) * 8 + hsub] = (_Float16)hv;

    // ---- prologue: rows r0..r0+5 -> slots 0..5; rows r0+6..r0+9 in flight ----
    SLOADM(r0 + srow) SWRITEM(srow)
    if (hact) { SLOADH(r0 + hrow) SWRITEH(hrow) }
    if (srow < 2) { SLOADM(r0 + 4 + srow) SWRITEM(4 + srow) }
    if (hact && hrow < 2) { SLOADH(r0 + 4 + hrow) SWRITEH(4 + hrow) }
    SLOADM(r0 + 6 + srow)
    if (hact) SLOADH(r0 + 6 + hrow)
    __syncthreads();

    const int roff = g2 * 68 + 32 * slice + l31;
    const size_t obase = (size_t)img * OH * OW;
    const int opx = base + 32 * slice + l31;

    int rs  = 0;                               // read base slot (row R)
    int wsM = 6 + srow;                        // write slot cursors
    int wsH = 6 + hrow;

#pragma unroll 1
    for (int t = 0; t < nit; ++t) {
        const int R = r0 + 4 * t;

        const f16x8* rp[6];
#pragma unroll
        for (int d = 0; d < 6; ++d) {
            int s = rs + d; if (s >= RING) s -= RING;
            rp[d] = ring + s * SROW + roff;
        }

        // ---- MFMA phase: 18 ds_reads -> 36 MFMAs, ro-interleaved chains ----
        f32x16 acc[4];
#pragma unroll
        for (int kw = 0; kw < 3; ++kw) {
            f16x8 f[6];
#pragma unroll
            for (int d = 0; d < 6; ++d) f[d] = rp[d][kw];
#pragma unroll
            for (int kh = 0; kh < 3; ++kh) {
#pragma unroll
                for (int ro = 0; ro < 4; ++ro) {
                    if (kh == 0 && kw == 0)
                        acc[ro] = __builtin_amdgcn_mfma_f32_32x32x16_f16(wreg[0], f[ro], cbias, 0, 0, 0);
                    else
                        acc[ro] = __builtin_amdgcn_mfma_f32_32x32x16_f16(wreg[kh * 3 + kw], f[ro + kh], acc[ro], 0, 0, 0);
                }
            }
        }

        // stage rows R+6..R+9 (loads were issued last iter; vmcnt window = MFMA phase)
        SWRITEM(wsM)
        if (hact) SWRITEH(wsH)

        // partial min over this wave's 32 couts, per out row
        float mn[4];
#pragma unroll
        for (int ro = 0; ro < 4; ++ro) {
            float v = fminf(acc[ro][0], acc[ro][1]);
#pragma unroll
            for (int q = 2; q < 16; q += 2) v = min3f(acc[ro][q], acc[ro][q + 1], v);
            v = fminf(v, __shfl_xor(v, 32));
            mn[ro] = v;
            if (lane < 32) xmin[t & 1][m][slice][ro][lane] = v;
        }

        __syncthreads();   // orders: ring publish + xmin exchange

        // combine halves, tanh(tanh), store (m=0 waves)
        if (m == 0) {
#pragma unroll
            for (int ro = 0; ro < 4; ++ro) {
                const int oh = R + ro;
                float o = fminf(mn[ro], xmin[t & 1][1][slice][ro][l31]);
                o = tanh_fast(tanh_fast(o));
                if (lane < 32 && oh < OH && opx < OW)
                    out[obase + (size_t)oh * OW + opx] = o;
            }
        }

        // issue loads for rows R+10..R+13 (consumed next iter)
        SLOADM(r0 + 4 * t + 10 + srow)
        if (hact) SLOADH(r0 + 4 * t + 10 + hrow)

        rs += 4;  if (rs >= RING) rs -= RING;
        wsM += 4; if (wsM >= RING) wsM -= RING;
        wsH += 4; if (wsH >= RING) wsH -= RING;
    }
}

extern "C" void kernel_launch(void* const* d_in, const int* in_sizes, int n_in,
                              void* d_out, int out_size, void* d_ws, size_t ws_size,
                              hipStream_t stream) {
    const float* x    = (const float*)d_in[0];
    const float* w    = (const float*)d_in[1];
    const float* bias = (const float*)d_in[2];
    float* out = (float*)d_out;
    _Float16* wpk = (_Float16*)d_ws;   // 9216 fp16 = 18,432 B

    wpack_kernel<<<36, 256, 0, stream>>>(w, wpk);
    conv_mfma_kernel<<<768, 256, 0, stream>>>(x, (const f16x8*)wpk, bias, out);
}

// Round 16
// 107.267 us; speedup vs baseline: 1.2794x; 1.2794x over previous
//
#include <hip/hip_runtime.h>
#include <math.h>

#define CIN   16
#define COUT  64
#define H     256
#define W     256
#define OH    254
#define OW    254
#define NTAP  9
#define HWSZ  (H * W)
#define RING  16
#define SROW  136      // f16x8 slots per ring row: 2 cin-halves * 68 px

typedef _Float16 f16x8  __attribute__((ext_vector_type(8)));
typedef float    f32x16 __attribute__((ext_vector_type(16)));

// weight pack: [tap 9][msub 2][lane 64][e 8] fp16; co=(l&31)+32m, cin=8*(l>>5)+e
__global__ void wpack_kernel(const float* __restrict__ w, _Float16* __restrict__ wpk) {
    int idx = blockIdx.x * 256 + threadIdx.x;   // 0..9215
    if (idx >= NTAP * 2 * 64 * 8) return;
    int e = idx & 7, l = (idx >> 3) & 63, m = (idx >> 9) & 1, t = idx >> 10;
    int co  = (l & 31) + 32 * m;
    int cin = 8 * (l >> 5) + e;
    wpk[idx] = (_Float16)w[((co * CIN + cin) * 3 + t / 3) * 3 + (t % 3)];
}

__device__ __forceinline__ float tanh_fast(float v) {
    float e = __expf(2.0f * v);
    return 1.0f - 2.0f * __builtin_amdgcn_rcpf(e + 1.0f);
}
__device__ __forceinline__ float min3f(float a, float b, float c) {
    return fminf(fminf(a, b), c);   // clang fuses to v_min3_f32
}

// 512 thr = 8 waves: waves 0-3 CONSUMERS (pure LDS->MFMA), waves 4-7 PRODUCERS
// (global->cvt->LDS; they eat all vmem latency). Block = (img, 64px col,
// 128-row half). 6 rows/iter, 22 iters, one barrier/iter. 16-row LDS ring.
__global__ __launch_bounds__(512, 2) void conv_mfma_kernel(
        const float* __restrict__ x, const f16x8* __restrict__ wpk,
        const float* __restrict__ bias, float* __restrict__ out) {
    __shared__ f16x8 ring[RING * SROW];        // 34,816 B
    __shared__ float xmin[2][2][2][6][32];     // 6,144 B [par][m][slice][rr][px]

    const int tid  = threadIdx.x;
    const int lane = tid & 63;
    const int wv   = tid >> 6;

    int bid = blockIdx.x;
    int nb  = (bid & 7) * 64 + (bid >> 3);     // 512 = 8*64 bijective XCD swizzle
    const int img  = nb >> 3;
    const int rem  = nb & 7;
    const int c    = rem & 3;                  // 64-px column
    const int half = rem >> 2;                 // 128-row half
    const int R0   = half * 128;
    const int base = 64 * c;

    const float* xb = x + (size_t)img * CIN * HWSZ;

    if (wv < 4) {
        // ==================== CONSUMERS ====================
        const int m     = wv & 1;
        const int slice = wv >> 1;
        const int l31   = lane & 31;
        const int g2    = lane >> 5;

        f16x8 wreg[NTAP];
#pragma unroll
        for (int t = 0; t < NTAP; ++t)
            wreg[t] = wpk[(t * 2 + m) * 64 + lane];

        f32x16 cbias;
#pragma unroll
        for (int q = 0; q < 16; ++q)
            cbias[q] = bias[(q & 3) + 8 * (q >> 2) + 4 * g2 + 32 * m];

        const int foff  = g2 * 68 + 32 * slice + l31;  // +kw via imm offset
        const int ohlim = half ? OH : 128;
        const int opx   = base + 32 * slice + l31;
        const size_t obase = (size_t)img * OH * OW;

#define CPASS(t, p)                                                             \
        {                                                                       \
            f16x8 f[5][3];                                                      \
            _Pragma("unroll")                                                   \
            for (int d = 0; d < 5; ++d) {                                       \
                const int rr = 6 * (t) + 3 * (p) + d;                           \
                const f16x8* rp = ring + (rr & 15) * SROW + foff;               \
                f[d][0] = rp[0]; f[d][1] = rp[1]; f[d][2] = rp[2];              \
            }                                                                   \
            f32x16 acc[3];                                                      \
            _Pragma("unroll")                                                   \
            for (int kw = 0; kw < 3; ++kw)                                      \
                _Pragma("unroll")                                               \
                for (int kh = 0; kh < 3; ++kh)                                  \
                    _Pragma("unroll")                                           \
                    for (int ro = 0; ro < 3; ++ro)                              \
                        acc[ro] = __builtin_amdgcn_mfma_f32_32x32x16_f16(       \
                            wreg[kh * 3 + kw], f[ro + kh][kw],                  \
                            (kh == 0 && kw == 0) ? cbias : acc[ro], 0, 0, 0);   \
            _Pragma("unroll")                                                   \
            for (int ro = 0; ro < 3; ++ro) {                                    \
                float mn = fminf(acc[ro][0], acc[ro][1]);                       \
                _Pragma("unroll")                                               \
                for (int q = 2; q < 16; q += 2)                                 \
                    mn = min3f(acc[ro][q], acc[ro][q + 1], mn);                 \
                mn = fminf(mn, __shfl_xor(mn, 32));                             \
                if (lane < 32) xmin[(t) & 1][m][slice][3 * (p) + ro][lane] = mn;\
            }                                                                   \
        }

#define EPI(tp)                                                                 \
        if (lane < 32 && opx < OW) {                                            \
            _Pragma("unroll")                                                   \
            for (int rr = 0; rr < 6; ++rr) {                                    \
                const int oh = R0 + 6 * (tp) + rr;                              \
                if (oh < ohlim) {                                               \
                    float v = fminf(xmin[(tp) & 1][0][slice][rr][l31],           \
                                    xmin[(tp) & 1][1][slice][rr][l31]);          \
                    v = tanh_fast(tanh_fast(v));                                \
                    out[obase + (size_t)oh * OW + opx] = v;                     \
                }                                                               \
            }                                                                   \
        }

        __syncthreads();                       // B_pre
#pragma unroll 1
        for (int t = 0; t < 22; ++t) {
            CPASS(t, 0)
            CPASS(t, 1)
            if (t > 0 && m == 0) EPI(t - 1)    // reads parity written before B_{t-1}
            __syncthreads();                   // B_t
        }
        if (m == 0) EPI(21)
    } else {
        // ==================== PRODUCERS ====================
        const int ptid = tid - 256;            // 0..255
        // unit decode: u = ptid + 256k over [g 2][row N][pair 34] rows-major:
        // row = u/68, rem = u%68, g = rem>=34, px2 = 2*(rem%34)
        int row_[3], g_[3], px2_[3];
#pragma unroll
        for (int k = 0; k < 3; ++k) {
            int u = ptid + 256 * k;
            row_[k] = u / 68;
            int r2 = u - 68 * row_[k];
            g_[k]  = (r2 >= 34) ? 1 : 0;
            px2_[k] = 2 * (r2 - 34 * g_[k]);
        }

#define PLOAD(k, rowbase, vv)                                                   \
        {                                                                       \
            int gr = (rowbase) + row_[k]; if (gr > 255) gr = 255;               \
            int gx = base + px2_[k];      if (gx > 254) gx = 254;               \
            const float* gp = xb + (size_t)(8 * g_[k]) * HWSZ                   \
                                 + (size_t)gr * W + gx;                         \
            _Pragma("unroll")                                                   \
            for (int cc = 0; cc < 8; ++cc)                                      \
                vv[cc] = *(const float2*)(gp + (size_t)cc * HWSZ);              \
        }

#define PWRITE(k, rowbase, vv)                                                  \
        {                                                                       \
            const int sl = ((rowbase) + row_[k]) & 15;                          \
            f16x8 q0, q1;                                                       \
            _Pragma("unroll")                                                   \
            for (int cc = 0; cc < 8; ++cc) { q0[cc] = (_Float16)vv[cc].x;       \
                                             q1[cc] = (_Float16)vv[cc].y; }     \
            const int ad = sl * SROW + g_[k] * 68 + px2_[k];                    \
            ring[ad]     = q0;                                                  \
            ring[ad + 1] = q1;                                                  \
        }

        float2 A0[8], A1[8], B0[8], B1[8];
        // prologue: rows R0..R0+7 (544 units: k0,k1 all; k2 ptid<32)
        {
            float2 C0[8];
            PLOAD(0, R0, A0)
            PLOAD(1, R0, A1)
            if (ptid < 32) PLOAD(2, R0, C0)
            PWRITE(0, R0, A0)
            PWRITE(1, R0, A1)
            if (ptid < 32) PWRITE(2, R0, C0)
        }
        // issue iter-0 set A: rows R0+8..R0+13 (408 units: k0 all, k1 ptid<152)
        PLOAD(0, R0 + 8, A0)
        if (ptid < 152) PLOAD(1, R0 + 8, A1)
        __syncthreads();                       // B_pre

#pragma unroll 1
        for (int j = 0; j < 11; ++j) {
            const int t0 = 2 * j, t1 = 2 * j + 1;
            // iter t0: write A (rows R0+6t0+8..13), issue B (rows for t0+1)
            PWRITE(0, R0 + 6 * t0 + 8, A0)
            if (ptid < 152) PWRITE(1, R0 + 6 * t0 + 8, A1)
            PLOAD(0, R0 + 6 * t0 + 14, B0)
            if (ptid < 152) PLOAD(1, R0 + 6 * t0 + 14, B1)
            __syncthreads();                   // B_{t0}
            // iter t1: write B, issue A (skip issue at the last iter)
            PWRITE(0, R0 + 6 * t1 + 8, B0)
            if (ptid < 152) PWRITE(1, R0 + 6 * t1 + 8, B1)
            if (t1 < 21) {
                PLOAD(0, R0 + 6 * t1 + 14, A0)
                if (ptid < 152) PLOAD(1, R0 + 6 * t1 + 14, A1)
            }
            __syncthreads();                   // B_{t1}
        }
    }
}

extern "C" void kernel_launch(void* const* d_in, const int* in_sizes, int n_in,
                              void* d_out, int out_size, void* d_ws, size_t ws_size,
                              hipStream_t stream) {
    const float* x    = (const float*)d_in[0];
    const float* w    = (const float*)d_in[1];
    const float* bias = (const float*)d_in[2];
    float* out = (float*)d_out;
    _Float16* wpk = (_Float16*)d_ws;   // 9216 fp16 = 18,432 B

    wpack_kernel<<<36, 256, 0, stream>>>(w, wpk);
    conv_mfma_kernel<<<512, 512, 0, stream>>>(x, (const f16x8*)wpk, bias, out);
}

// Round 17
// 91.643 us; speedup vs baseline: 1.4976x; 1.1705x over previous
//
#include <hip/hip_runtime.h>
#include <math.h>

#define CIN   16
#define COUT  64
#define H     256
#define W     256
#define OH    254
#define OW    254
#define NTAP  9
#define HWSZ  (H * W)
#define RING  18
#define SROW  136        // f16x8 slots per ring row: 2 cin-halves * 68 px

typedef _Float16 f16x8  __attribute__((ext_vector_type(8)));
typedef float    f32x16 __attribute__((ext_vector_type(16)));

// weight pack: [tap 9][msub 2][lane 64][e 8] fp16; co=(l&31)+32m, cin=8*(l>>5)+e
__global__ void wpack_kernel(const float* __restrict__ w, _Float16* __restrict__ wpk) {
    int idx = blockIdx.x * 256 + threadIdx.x;   // 0..9215
    if (idx >= NTAP * 2 * 64 * 8) return;
    int e = idx & 7, l = (idx >> 3) & 63, m = (idx >> 9) & 1, t = idx >> 10;
    int co  = (l & 31) + 32 * m;
    int cin = 8 * (l >> 5) + e;
    wpk[idx] = (_Float16)w[((co * CIN + cin) * 3 + t / 3) * 3 + (t % 3)];
}

__device__ __forceinline__ float tanh_fast(float v) {
    float e = __expf(2.0f * v);
    return 1.0f - 2.0f * __builtin_amdgcn_rcpf(e + 1.0f);
}
__device__ __forceinline__ float min3f(float a, float b, float c) {
    return fminf(fminf(a, b), c);   // clang fuses to v_min3_f32
}

// 256 thr = 4 waves (2 px-slices x 2 row-groups, full 64-cout per wave).
// Persistent block = (img, 64px col, 128-row half); 16 tiles of 8 out-rows.
// 18-row LDS ring: compute(rows 8t..8t+9) || PWRITE(8t+10..17, regs from
// last tile) || PLOAD(8t+18..25 into regs). Slots disjoint -> 1 barrier/tile.
__global__ __launch_bounds__(256, 2) void conv_mfma_kernel(
        const float* __restrict__ x, const f16x8* __restrict__ wpk,
        const float* __restrict__ bias, float* __restrict__ out) {
    __shared__ f16x8 ring[RING * SROW];    // 39,168 B
    __shared__ float bias_lds[64];         // [g2][m][q] pre-arranged

    const int tid  = threadIdx.x;
    const int lane = tid & 63;

    int bid = blockIdx.x;
    int nb  = (bid & 7) * 64 + (bid >> 3);     // 512 = 8*64 bijective XCD swizzle
    const int img  = nb >> 3;
    const int rem  = nb & 7;
    const int colb = rem & 3;                  // 64-px column
    const int half = rem >> 2;                 // 128-row half
    const int base = 64 * colb;
    const int R0   = 128 * half;
    const int S0   = half ? 2 : 0;             // R0 % 18

    const float* xb = x + (size_t)img * CIN * HWSZ;

    // ---- weights: full 64 cout -> 72 VGPRs ----
    f16x8 wreg[NTAP][2];
#pragma unroll
    for (int t = 0; t < NTAP; ++t)
#pragma unroll
        for (int m = 0; m < 2; ++m)
            wreg[t][m] = wpk[(t * 2 + m) * 64 + lane];

    // bias -> LDS in lane layout: bias_lds[g2*32+m*16+q] = bias[(q&3)+8*(q>>2)+4*g2+32*m]
    if (tid < 64) {
        int q = tid & 15, m = (tid >> 4) & 1, g = tid >> 5;
        bias_lds[tid] = bias[(q & 3) + 8 * (q >> 2) + 4 * g + 32 * m];
    }

    // ---- staging unit decode: u = tid + 256k over [row8 0..7][r2 0..67] ----
    int r8[3], gq[3], gx[3], wof[3];
#pragma unroll
    for (int k = 0; k < 3; ++k) {
        int u  = tid + 256 * k;
        r8[k]  = u / 68;
        int r2 = u - 68 * r8[k];
        int g  = (r2 >= 34) ? 1 : 0;
        int p  = r2 - 34 * g;
        int px = base + 2 * p; if (px > 254) px = 254;
        gq[k]  = g;
        gx[k]  = px;
        wof[k] = g * 68 + 2 * p;
    }
    const bool act2 = (tid < 32);              // 544 - 512 units

    float2 vA[8], vB[8], vC[8];

#define PLOADK(k, rowAbs, vv)                                                   \
    {                                                                           \
        int gr = (rowAbs); if (gr > 255) gr = 255;                              \
        const float* gp = xb + (size_t)(8 * gq[k]) * HWSZ + (size_t)gr * W + gx[k]; \
        _Pragma("unroll")                                                       \
        for (int cc = 0; cc < 8; ++cc) vv[cc] = *(const float2*)(gp + (size_t)cc * HWSZ); \
    }

#define PWRITEK(k, slot, vv)                                                    \
    {                                                                           \
        f16x8 q0, q1;                                                           \
        _Pragma("unroll")                                                       \
        for (int cc = 0; cc < 8; ++cc) { q0[cc] = (_Float16)vv[cc].x;           \
                                         q1[cc] = (_Float16)vv[cc].y; }         \
        const int ad = (slot) * SROW + wof[k];                                  \
        ring[ad]     = q0;                                                      \
        ring[ad + 1] = q1;                                                      \
    }

    // ---- prologue: stage rows R0..R0+9 (680 units over 3 rounds) ----
#pragma unroll
    for (int k = 0; k < 3; ++k) {
        int u = tid + 256 * k;
        if (k == 2 && tid >= 168) break;
        int r10 = u / 68;
        int r2  = u - 68 * r10;
        int g   = (r2 >= 34) ? 1 : 0;
        int p   = r2 - 34 * g;
        int px  = base + 2 * p; if (px > 254) px = 254;
        const float* gp = xb + (size_t)(8 * g) * HWSZ + (size_t)(R0 + r10) * W + px;
        float2 vm[8];
#pragma unroll
        for (int cc = 0; cc < 8; ++cc) vm[cc] = *(const float2*)(gp + (size_t)cc * HWSZ);
        f16x8 q0, q1;
#pragma unroll
        for (int cc = 0; cc < 8; ++cc) { q0[cc] = (_Float16)vm[cc].x;
                                         q1[cc] = (_Float16)vm[cc].y; }
        const int ad = (S0 + r10) * SROW + g * 68 + 2 * p;
        ring[ad]     = q0;
        ring[ad + 1] = q1;
    }

    // initial prefetch: rows R0+10+r8 (PWRITten at tile 0)
    PLOADK(0, R0 + 10 + r8[0], vA)
    PLOADK(1, R0 + 10 + r8[1], vB)
    if (act2) PLOADK(2, R0 + 10 + r8[2], vC)
    __syncthreads();

    const int wv  = tid >> 6;
    const int s   = wv & 1;                    // 32-px slice
    const int rg  = wv >> 1;                   // 4-row group
    const int l31 = lane & 31;
    const int g2  = lane >> 5;
    const int foff = g2 * 68 + 32 * s + l31;
    const int opx  = base + 32 * s + l31;
    const size_t obase = (size_t)img * OH * OW;
    const f32x16* bp = (const f32x16*)(bias_lds + g2 * 32);

    int slot0 = S0;

#pragma unroll 1
    for (int t = 0; t < 16; ++t) {
        const int row0 = R0 + 8 * t;

        // ---- compute: 2 chunks x 2 rows (reads ring rows 8t..8t+9) ----
#pragma unroll
        for (int c = 0; c < 2; ++c) {
            const int rowoff = 4 * rg + 2 * c;
            f32x16 cb0 = bp[0], cb1 = bp[1];   // C-operands from LDS
            f32x16 acc[2][2];
#pragma unroll
            for (int dd = 0; dd < 4; ++dd) {
                int sl = slot0 + rowoff + dd; if (sl >= RING) sl -= RING;
                const f16x8* rp = ring + sl * SROW + foff;
                f16x8 f0 = rp[0], f1 = rp[1], f2 = rp[2];
#pragma unroll
                for (int kw = 0; kw < 3; ++kw) {
                    f16x8 ff = (kw == 0) ? f0 : (kw == 1) ? f1 : f2;
#pragma unroll
                    for (int ro = 0; ro < 2; ++ro) {
                        const int kh = dd - ro;
                        if (kh < 0 || kh > 2) continue;
#pragma unroll
                        for (int m = 0; m < 2; ++m) {
                            const f32x16& cin_ = (kh == 0 && kw == 0)
                                               ? (m == 0 ? cb0 : cb1) : acc[ro][m];
                            acc[ro][m] = __builtin_amdgcn_mfma_f32_32x32x16_f16(
                                wreg[kh * 3 + kw][m], ff, cin_, 0, 0, 0);
                        }
                    }
                }
            }
            // epilogue: min over 64 cout -> tanh(tanh) -> store
#pragma unroll
            for (int ro = 0; ro < 2; ++ro) {
                float mn = fminf(acc[ro][0][0], acc[ro][1][0]);
#pragma unroll
                for (int q = 1; q < 16; ++q)
                    mn = min3f(acc[ro][0][q], acc[ro][1][q], mn);
                mn = fminf(mn, __shfl_xor(mn, 32));
                float t2 = tanh_fast(tanh_fast(mn));
                const int oh = row0 + rowoff + ro;
                if (g2 == 0 && oh < OH && opx < OW)
                    out[obase + (size_t)oh * OW + opx] = t2;
            }
        }

        // ---- stage: write rows 8t+10..17 (slots disjoint from read slots) ----
        if (t <= 14) {
            int sl0 = slot0 + 10 + r8[0]; if (sl0 >= RING) sl0 -= RING;
            int sl1 = slot0 + 10 + r8[1]; if (sl1 >= RING) sl1 -= RING;
            PWRITEK(0, sl0, vA)
            PWRITEK(1, sl1, vB)
            if (act2) {
                int sl2 = slot0 + 10 + r8[2]; if (sl2 >= RING) sl2 -= RING;
                PWRITEK(2, sl2, vC)
            }
        }
        // ---- issue loads for rows 8t+18..25 (consumed next tile) ----
        if (t <= 13) {
            PLOADK(0, row0 + 18 + r8[0], vA)
            PLOADK(1, row0 + 18 + r8[1], vB)
            if (act2) PLOADK(2, row0 + 18 + r8[2], vC)
        }
        __syncthreads();
        slot0 += 8; if (slot0 >= RING) slot0 -= RING;
    }
}

extern "C" void kernel_launch(void* const* d_in, const int* in_sizes, int n_in,
                              void* d_out, int out_size, void* d_ws, size_t ws_size,
                              hipStream_t stream) {
    const float* x    = (const float*)d_in[0];
    const float* w    = (const float*)d_in[1];
    const float* bias = (const float*)d_in[2];
    float* out = (float*)d_out;
    _Float16* wpk = (_Float16*)d_ws;   // 9216 fp16 = 18,432 B

    wpack_kernel<<<36, 256, 0, stream>>>(w, wpk);
    conv_mfma_kernel<<<512, 256, 0, stream>>>(x, (const f16x8*)wpk, bias, out);
}